// Round 22
// baseline (40.864 us; speedup 1.0000x reference)
//
#include <hip/hip_runtime.h>

// BinaryTreeShConv on MI355X (gfx950).
// out[b,v,i] = relu(bias[i] + sum_{p,c,rn} W[i,c,rn] * K[b,v,p,rn] * sig[b, idx[b,v,p], c])
// B=8 V=4096 P=32 C=32 RN=32 OUT=32, CRN=1024.
//
// R21 = R19 (best, 34.9) with the sigbf stage removed:
//  - gathers read the HIGH USHORT of each f32 sig element directly
//    (ushort idx 2e+1 = truncate-to-bf16; same 2-byte loads, zero VALU) —
//    the same trick R1 proved on ck. sig L2 footprint/XCD = 512 KB << 4 MB.
//  - prep = Wf pack only (128 blocks, ~1 us) -> removes ~1.5-2 us of
//    serialized prep (640 blocks, 6 MB) from the critical path.
// Everything else byte-identical to R19: XCD-chunked swizzle, 512thr/8bv,
// 2 barriers, ckb/red aliasing, launch_bounds(512,8), grid 4096.
// Numerics: sig truncated (was RNE) -> absmax ~0.3-0.5 expected (thr 0.865).

typedef __attribute__((ext_vector_type(8))) short bf16x8;
typedef __attribute__((ext_vector_type(4))) short short4v;
typedef __attribute__((ext_vector_type(16))) float f32x16;
typedef __attribute__((ext_vector_type(4))) float f32x4;

__device__ __forceinline__ unsigned short f2bf_rne(float f) {
    union { float f; unsigned int u; } x;
    x.f = f;
    unsigned int u = x.u;
    return (unsigned short)((u + 0x7fffu + ((u >> 16) & 1u)) >> 16);
}
__device__ __forceinline__ unsigned short f2bf_rh(float f) {  // round-half-up
    union { float f; unsigned int u; } x;
    x.f = f;
    return (unsigned short)((x.u + 0x8000u) >> 16);
}

// Wf[pair=2s+t][lane][j] = bf16(W[i=16t+(lane&15)][crn=32s+8*(lane>>4)+j])
__global__ __launch_bounds__(256) void prep_kernel(
        const float* __restrict__ W, unsigned short* __restrict__ Wf) {
    int tid = blockIdx.x * 256 + threadIdx.x;   // 0..32767
    int j = tid & 7;
    int l = (tid >> 3) & 63;
    int pair = tid >> 9;                        // s*2 + t
    int s = pair >> 1;
    int t = pair & 1;
    int i = 16 * t + (l & 15);
    int crn = 32 * s + 8 * (l >> 4) + j;
    Wf[tid] = f2bf_rne(W[i * 1024 + crn]);
}

__global__ __launch_bounds__(512, 8) void fused_kernel(
        const float* __restrict__ sig, const int* __restrict__ pidx,
        const float* __restrict__ ck, const unsigned short* __restrict__ Wf,
        const float* __restrict__ bias, float* __restrict__ out) {
    __shared__ __align__(16) unsigned short ckb[8 * 1024];   // ck tiles, then red
    __shared__ __align__(16) unsigned short T_lds[8 * 1032]; // 16,512 B
    const int tid = threadIdx.x;
    const int l = tid & 63;
    const int g = l >> 5;
    const int cc = l & 31;
    const int wu = __builtin_amdgcn_readfirstlane(tid >> 6);  // wave 0..7 (SGPR)
    // XCD-chunked bijective swizzle: 4096 blocks = 8 XCDs x 512.
    const int bid = blockIdx.x;
    const int swz = (bid & 7) * 512 + (bid >> 3);
    const int m0 = swz * 8;          // 8 bv per block (same b)
    const int b = m0 >> 12;
    // hi-ushort view of this batch's sig slice: element e -> ushort 2e+1
    const unsigned short* sgh =
        (const unsigned short*)(sig + (size_t)b * (4096 * 32));

    // ======== Phase 0: pure streaming; wave wu owns bv wu ========
    // (a) idx: wave-uniform scalar loads (32 ints -> SGPRs)
    int rows[32];
    {
        const int* ip = pidx + (size_t)(m0 + wu) * 32;
        #pragma unroll
        for (int k = 0; k < 32; ++k) rows[k] = ip[k];
    }
    // (b) ck staging for bv wu: 4 KB = 4 f32x4 per lane, issued up front
    f32x4 st[4];
    {
        const f32x4* ckv = (const f32x4*)(ck + (size_t)(m0 + wu) * 1024);
        #pragma unroll
        for (int i = 0; i < 4; ++i) st[i] = ckv[i * 64 + l];
    }
    // (c) gathers: 16 per lane (1 bv), hi-ushort of f32 sig (truncate-to-bf16,
    //     zero VALU); const-indexed rows + g?hi:lo cndmask (rule #20)
    unsigned short ga[16];
    #pragma unroll
    for (int h = 0; h < 2; ++h) {
        #pragma unroll
        for (int j = 0; j < 8; ++j) {
            const int rlo = rows[h * 16 + j];
            const int rhi = rows[h * 16 + 8 + j];
            const int row = g ? rhi : rlo;
            ga[h * 8 + j] = sgh[(((size_t)row * 32 + cc) << 1) | 1];
        }
    }
    // (d) pack ck staging to bf16 -> LDS (linear, coalesced b64).
    //     NO barrier: wave wu writes only ckb[wu], phase A reads only ckb[wu].
    #pragma unroll
    for (int i = 0; i < 4; ++i) {
        union { f32x4 f; unsigned int u[4]; } x;
        x.f = st[i];
        short4v v = { (short)(x.u[0] >> 16), (short)(x.u[1] >> 16),
                      (short)(x.u[2] >> 16), (short)(x.u[3] >> 16) };
        *(short4v*)(ckb + wu * 1024 + (i * 64 + l) * 4) = v;
    }

    // ======== Phase A: stage-A MFMA; wave wu computes T for bv wu ========
    {
        const unsigned short* ct = ckb + wu * 1024;   // [32p][32rn], own region
        f32x16 acc = {};
        #pragma unroll
        for (int h = 0; h < 2; ++h) {
            bf16x8 af, bfr;
            #pragma unroll
            for (int j = 0; j < 8; ++j) {
                const int p = h * 16 + 8 * g + j;
                af[j]  = (short)ga[h * 8 + j];
                bfr[j] = (short)ct[p * 32 + cc];
            }
            acc = __builtin_amdgcn_mfma_f32_32x32x16_bf16(af, bfr, acc, 0, 0, 0);
        }
        // D map (verified): col=cc, row=(r&3)+8*(r>>2)+4*g ; T[c][rn] bf16
        unsigned short* trow = T_lds + wu * 1032 + cc + g * 128;
        #pragma unroll
        for (int r = 0; r < 16; ++r)
            trow[((r & 3) + 8 * (r >> 2)) * 32] = f2bf_rh(acc[r]);
    }
    __syncthreads();   // barrier 1: all T rows visible to all waves

    // ======== Phase B: k-split s = 4wu..4wu+3, both i-tiles ========
    // A-frag row ln -> T row (ln&7); rows 8-15 broadcast-duplicate 0-7.
    f32x4 acc0 = {}, acc1 = {};
    const int lg = l >> 4;
    const int ln = l & 15;
    #pragma unroll
    for (int si = 0; si < 4; ++si) {
        const int s = 4 * wu + si;
        const bf16x8 af =
            *(const bf16x8*)(T_lds + (ln & 7) * 1032 + s * 32 + 8 * lg);
        const bf16x8* wrow = (const bf16x8*)(Wf + (size_t)(s * 2) * 512);
        const bf16x8 b0 = wrow[l];        // pair 2s+0, 16B/lane coalesced, L2-hot
        const bf16x8 b1 = wrow[64 + l];   // pair 2s+1
        acc0 = __builtin_amdgcn_mfma_f32_16x16x32_bf16(af, b0, acc0, 0, 0, 0);
        acc1 = __builtin_amdgcn_mfma_f32_16x16x32_bf16(af, b1, acc1, 0, 0, 0);
    }

    // red buffer = ckb (dead after phase A; wave wu overwrites only the
    // region it alone read) — no barrier between T reads and these writes.
    float* red = (float*)ckb;             // 8 waves * 512 f32 = 16,384 B exact
    {
        f32x4* rp = (f32x4*)(red + wu * 512);
        rp[l]      = acc0;                // [w][t=0][l][r]
        rp[64 + l] = acc1;                // [w][t=1][l][r]
    }
    __syncthreads();   // barrier 2: red complete

    // 256 outputs: threads 0-255 -> (bv = tid>>5, i = tid&31); 8-way k-sum.
    if (tid < 256) {
        const int bv  = tid >> 5;
        const int i   = tid & 31;
        const int t   = i >> 4;
        const int col = i & 15;
        const int lgi = bv >> 2;          // 0..1
        const int r   = bv & 3;
        const int li  = lgi * 16 + col;
        const int o   = t * 256 + li * 4 + r;
        float sum = 0.f;
        #pragma unroll
        for (int w2 = 0; w2 < 8; ++w2) sum += red[w2 * 512 + o];
        sum += bias[i];
        out[(size_t)(m0 + bv) * 32 + i] = sum > 0.f ? sum : 0.f;
    }
}

extern "C" void kernel_launch(void* const* d_in, const int* in_sizes, int n_in,
                              void* d_out, int out_size, void* d_ws, size_t ws_size,
                              hipStream_t stream) {
    const float* sig  = (const float*)d_in[0];
    const int*   pidx = (const int*)d_in[1];
    const float* ck   = (const float*)d_in[2];
    const float* W    = (const float*)d_in[3];
    const float* bias = (const float*)d_in[4];
    float* out = (float*)d_out;
    unsigned short* Wf = (unsigned short*)d_ws;   // 64 KB fragment-ordered W

    prep_kernel<<<128, 256, 0, stream>>>(W, Wf);
    fused_kernel<<<4096, 512, 0, stream>>>(sig, pidx, ck, Wf, bias, out);
}

// Round 23
// 34.998 us; speedup vs baseline: 1.1676x; 1.1676x over previous
//
#include <hip/hip_runtime.h>

// BinaryTreeShConv on MI355X (gfx950).
// out[b,v,i] = relu(bias[i] + sum_{p,c,rn} W[i,c,rn] * K[b,v,p,rn] * sig[b, idx[b,v,p], c])
// B=8 V=4096 P=32 C=32 RN=32 OUT=32, CRN=1024.
//
// R22 = exact restoration of R19 (champion, 34.9 us). R20 (16-wave blocks)
// was neutral; R21 (drop sigbf, gather f32-hi-ushort) regressed 6 us via
// doubled gather line footprint. This is the terminal structure:
//  - XCD-chunked bijective swizzle: swz = (bid&7)*512 + (bid>>3)
//  - 512 thr / 8 waves / 8 bv; wave owns 1 bv in phases 0/A
//  - phase 0 pure streaming (idx s_loads -> ck f32x4 -> u16 gathers from
//    compact sigbf -> LDS pack), no barrier before phase A (own-region RAW)
//  - phase B k-split 4 s/wave; red aliases consumed ckb; 2 barriers total
//  - prep: Wf fragment pack + sig->bf16 (RNE), 640 blocks
// absmax 0.25 expected.

typedef __attribute__((ext_vector_type(8))) short bf16x8;
typedef __attribute__((ext_vector_type(4))) short short4v;
typedef __attribute__((ext_vector_type(16))) float f32x16;
typedef __attribute__((ext_vector_type(4))) float f32x4;

__device__ __forceinline__ unsigned short f2bf_rne(float f) {
    union { float f; unsigned int u; } x;
    x.f = f;
    unsigned int u = x.u;
    return (unsigned short)((u + 0x7fffu + ((u >> 16) & 1u)) >> 16);
}
__device__ __forceinline__ unsigned short f2bf_rh(float f) {  // round-half-up
    union { float f; unsigned int u; } x;
    x.f = f;
    return (unsigned short)((x.u + 0x8000u) >> 16);
}

// Wf[pair=2s+t][lane][j] = bf16(W[i=16t+(lane&15)][crn=32s+8*(lane>>4)+j])
// plus sig f32 -> bf16 (RNE), 8 elements/thread.
__global__ __launch_bounds__(256) void prep_kernel(
        const float* __restrict__ W, const float* __restrict__ sig,
        unsigned short* __restrict__ Wf, unsigned short* __restrict__ sigbf) {
    int tid = blockIdx.x * 256 + threadIdx.x;
    if (tid < 32768) {
        int j = tid & 7;
        int l = (tid >> 3) & 63;
        int pair = tid >> 9;                    // s*2 + t
        int s = pair >> 1;
        int t = pair & 1;
        int i = 16 * t + (l & 15);
        int crn = 32 * s + 8 * (l >> 4) + j;
        Wf[tid] = f2bf_rne(W[i * 1024 + crn]);
    } else {
        int e = (tid - 32768) * 8;              // sig has 1,048,576 elements
        if (e < 8 * 4096 * 32) {
            f32x4 a = *(const f32x4*)(sig + e);
            f32x4 b = *(const f32x4*)(sig + e + 4);
            bf16x8 v;
            v[0] = (short)f2bf_rne(a[0]); v[1] = (short)f2bf_rne(a[1]);
            v[2] = (short)f2bf_rne(a[2]); v[3] = (short)f2bf_rne(a[3]);
            v[4] = (short)f2bf_rne(b[0]); v[5] = (short)f2bf_rne(b[1]);
            v[6] = (short)f2bf_rne(b[2]); v[7] = (short)f2bf_rne(b[3]);
            *(bf16x8*)(sigbf + e) = v;
        }
    }
}

__global__ __launch_bounds__(512, 8) void fused_kernel(
        const unsigned short* __restrict__ sigbf, const int* __restrict__ pidx,
        const float* __restrict__ ck, const unsigned short* __restrict__ Wf,
        const float* __restrict__ bias, float* __restrict__ out) {
    __shared__ __align__(16) unsigned short ckb[8 * 1024];   // ck tiles, then red
    __shared__ __align__(16) unsigned short T_lds[8 * 1032]; // 16,512 B
    const int tid = threadIdx.x;
    const int l = tid & 63;
    const int g = l >> 5;
    const int cc = l & 31;
    const int wu = __builtin_amdgcn_readfirstlane(tid >> 6);  // wave 0..7 (SGPR)
    // XCD-chunked bijective swizzle: 4096 blocks = 8 XCDs x 512.
    const int bid = blockIdx.x;
    const int swz = (bid & 7) * 512 + (bid >> 3);
    const int m0 = swz * 8;          // 8 bv per block (same b)
    const int b = m0 >> 12;
    const unsigned short* sgb = sigbf + (size_t)b * (4096 * 32);

    // ======== Phase 0: pure streaming; wave wu owns bv wu ========
    // (a) idx: wave-uniform scalar loads (32 ints -> SGPRs)
    int rows[32];
    {
        const int* ip = pidx + (size_t)(m0 + wu) * 32;
        #pragma unroll
        for (int k = 0; k < 32; ++k) rows[k] = ip[k];
    }
    // (b) ck staging for bv wu: 4 KB = 4 f32x4 per lane, issued up front
    f32x4 st[4];
    {
        const f32x4* ckv = (const f32x4*)(ck + (size_t)(m0 + wu) * 1024);
        #pragma unroll
        for (int i = 0; i < 4; ++i) st[i] = ckv[i * 64 + l];
    }
    // (c) gathers: 16 per lane (1 bv), u16 from sigbf; const-indexed rows
    //     + g?hi:lo cndmask (rule #20)
    unsigned short ga[16];
    #pragma unroll
    for (int h = 0; h < 2; ++h) {
        #pragma unroll
        for (int j = 0; j < 8; ++j) {
            const int rlo = rows[h * 16 + j];
            const int rhi = rows[h * 16 + 8 + j];
            const int row = g ? rhi : rlo;
            ga[h * 8 + j] = sgb[row * 32 + cc];
        }
    }
    // (d) pack ck staging to bf16 -> LDS (linear, coalesced b64).
    //     NO barrier: wave wu writes only ckb[wu], phase A reads only ckb[wu]
    //     — intra-wave RAW, in-order DS ops + lgkmcnt suffice.
    #pragma unroll
    for (int i = 0; i < 4; ++i) {
        union { f32x4 f; unsigned int u[4]; } x;
        x.f = st[i];
        short4v v = { (short)(x.u[0] >> 16), (short)(x.u[1] >> 16),
                      (short)(x.u[2] >> 16), (short)(x.u[3] >> 16) };
        *(short4v*)(ckb + wu * 1024 + (i * 64 + l) * 4) = v;
    }

    // ======== Phase A: stage-A MFMA; wave wu computes T for bv wu ========
    {
        const unsigned short* ct = ckb + wu * 1024;   // [32p][32rn], own region
        f32x16 acc = {};
        #pragma unroll
        for (int h = 0; h < 2; ++h) {
            bf16x8 af, bfr;
            #pragma unroll
            for (int j = 0; j < 8; ++j) {
                const int p = h * 16 + 8 * g + j;
                af[j]  = (short)ga[h * 8 + j];
                bfr[j] = (short)ct[p * 32 + cc];
            }
            acc = __builtin_amdgcn_mfma_f32_32x32x16_bf16(af, bfr, acc, 0, 0, 0);
        }
        // D map (verified): col=cc, row=(r&3)+8*(r>>2)+4*g ; T[c][rn] bf16
        unsigned short* trow = T_lds + wu * 1032 + cc + g * 128;
        #pragma unroll
        for (int r = 0; r < 16; ++r)
            trow[((r & 3) + 8 * (r >> 2)) * 32] = f2bf_rh(acc[r]);
    }
    __syncthreads();   // barrier 1: all T rows visible to all waves

    // ======== Phase B: k-split s = 4wu..4wu+3, both i-tiles ========
    // A-frag row ln -> T row (ln&7); rows 8-15 broadcast-duplicate 0-7.
    f32x4 acc0 = {}, acc1 = {};
    const int lg = l >> 4;
    const int ln = l & 15;
    #pragma unroll
    for (int si = 0; si < 4; ++si) {
        const int s = 4 * wu + si;
        const bf16x8 af =
            *(const bf16x8*)(T_lds + (ln & 7) * 1032 + s * 32 + 8 * lg);
        const bf16x8* wrow = (const bf16x8*)(Wf + (size_t)(s * 2) * 512);
        const bf16x8 b0 = wrow[l];        // pair 2s+0, 16B/lane coalesced, L2-hot
        const bf16x8 b1 = wrow[64 + l];   // pair 2s+1
        acc0 = __builtin_amdgcn_mfma_f32_16x16x32_bf16(af, b0, acc0, 0, 0, 0);
        acc1 = __builtin_amdgcn_mfma_f32_16x16x32_bf16(af, b1, acc1, 0, 0, 0);
    }

    // red buffer = ckb (dead after phase A; wave wu overwrites only the
    // region it alone read) — no barrier between T reads and these writes.
    float* red = (float*)ckb;             // 8 waves * 512 f32 = 16,384 B exact
    {
        f32x4* rp = (f32x4*)(red + wu * 512);
        rp[l]      = acc0;                // [w][t=0][l][r]
        rp[64 + l] = acc1;                // [w][t=1][l][r]
    }
    __syncthreads();   // barrier 2: red complete

    // 256 outputs: threads 0-255 -> (bv = tid>>5, i = tid&31); 8-way k-sum.
    if (tid < 256) {
        const int bv  = tid >> 5;
        const int i   = tid & 31;
        const int t   = i >> 4;
        const int col = i & 15;
        const int lgi = bv >> 2;          // 0..1
        const int r   = bv & 3;
        const int li  = lgi * 16 + col;
        const int o   = t * 256 + li * 4 + r;
        float sum = 0.f;
        #pragma unroll
        for (int w2 = 0; w2 < 8; ++w2) sum += red[w2 * 512 + o];
        sum += bias[i];
        out[(size_t)(m0 + bv) * 32 + i] = sum > 0.f ? sum : 0.f;
    }
}

extern "C" void kernel_launch(void* const* d_in, const int* in_sizes, int n_in,
                              void* d_out, int out_size, void* d_ws, size_t ws_size,
                              hipStream_t stream) {
    const float* sig  = (const float*)d_in[0];
    const int*   pidx = (const int*)d_in[1];
    const float* ck   = (const float*)d_in[2];
    const float* W    = (const float*)d_in[3];
    const float* bias = (const float*)d_in[4];
    float* out = (float*)d_out;
    unsigned short* Wf    = (unsigned short*)d_ws;       // 64 KB fragment-ordered W
    unsigned short* sigbf = Wf + 32768;                  // 2 MB bf16 signal

    prep_kernel<<<640, 256, 0, stream>>>(W, sig, Wf, sigbf);
    fused_kernel<<<4096, 512, 0, stream>>>(sigbf, pidx, ck, Wf, bias, out);
}